// Round 1
// baseline (369.484 us; speedup 1.0000x reference)
//
#include <hip/hip_runtime.h>

// Fold (col2im): x (8, 32, 8, 8, 4096) f32, kernel (8,8), stride (4,4),
// patch grid 64x64 -> out (8, 32, 260, 260) f32.
//
// Gather formulation: out[bc, h, w] = sum over (di,i) with h = 4i+di and
// (dj,j) with w = 4j+dj of x[bc, di, dj, i*64+j]. Each input element maps to
// exactly one output pixel, so total HBM traffic is read-input-once +
// write-output-once (no atomics, no overfetch).
//
// Thread layout: one thread produces 4 consecutive w outputs (w = 4t..4t+3,
// t in 0..64). Its dj=0..3 loads use j=t, dj=4..7 loads use j=t-1. Across
// consecutive threads t is consecutive -> contiguous coalesced reads per
// (di,dj) plane. Output written as one aligned float4 (row length 260 = 4*65).

#define N_PATCH 64      // patch grid n
#define L       4096    // n*n
#define H_OUT   260     // 4*(64-1)+8
#define T_BLK   65      // 260/4 w-quads per row
#define BC      256     // 8*32 fused batch*channel

__global__ __launch_bounds__(256) void fold_kernel(const float* __restrict__ x,
                                                   float* __restrict__ out) {
    int idx = blockIdx.x * blockDim.x + threadIdx.x;
    // idx in [0, BC * H_OUT * T_BLK) = [0, 4,326,400); launched exactly.
    int t    = idx % T_BLK;          // w-quad index, w = 4t + (0..3)
    int rest = idx / T_BLK;
    int h    = rest % H_OUT;
    int bc   = rest / H_OUT;         // 0..255

    float acc0 = 0.f, acc1 = 0.f, acc2 = 0.f, acc3 = 0.f;

    int r  = h & 3;                  // h % 4
    int i0 = h >> 2;                 // floor(h/4)

    // x flat index: ((bc*64 + di*8 + dj) * 4096) + i*64 + j
    int xb = bc * (64 * L);

    #pragma unroll
    for (int p = 0; p < 2; ++p) {
        int di = r + 4 * p;          // di = h%4 or h%4+4
        int i  = i0 - p;             // matching patch row
        if ((unsigned)i < (unsigned)N_PATCH) {
            int base = xb + di * (8 * L) + i * N_PATCH;
            if (t < N_PATCH) {       // j = t valid for dj = 0..3
                int a = base + t;
                acc0 += x[a + 0 * L];
                acc1 += x[a + 1 * L];
                acc2 += x[a + 2 * L];
                acc3 += x[a + 3 * L];
            }
            if (t >= 1) {            // j = t-1 valid for dj = 4..7
                int a = base + t - 1;
                acc0 += x[a + 4 * L];
                acc1 += x[a + 5 * L];
                acc2 += x[a + 6 * L];
                acc3 += x[a + 7 * L];
            }
        }
    }

    int ob = (bc * H_OUT + h) * H_OUT + 4 * t;   // 16B-aligned (4 | ob)
    float4 v = make_float4(acc0, acc1, acc2, acc3);
    *reinterpret_cast<float4*>(out + ob) = v;
}

extern "C" void kernel_launch(void* const* d_in, const int* in_sizes, int n_in,
                              void* d_out, int out_size, void* d_ws, size_t ws_size,
                              hipStream_t stream) {
    const float* x = (const float*)d_in[0];
    float* out     = (float*)d_out;

    const int total  = BC * H_OUT * T_BLK;   // 4,326,400 threads
    const int block  = 256;
    const int grid   = total / block;        // 16,900 (divides exactly)

    fold_kernel<<<grid, block, 0, stream>>>(x, out);
}